// Round 5
// baseline (235.436 us; speedup 1.0000x reference)
//
#include <hip/hip_runtime.h>

// AnomalyAttention forward, MI355X gfx950.
// B=8, N=1024, D=1024. Out = [Z (8*1024*1024 f32), P (8*1024*1024 f32)].
// Round 5: algebraic QK elimination (scores = (x*G)*x^T, G = Wk*Wq^T),
// all GEMMs on m97-style 128x128/BK=32/4-wave kernel (~5 blocks/CU),
// xq+VT fused into one 1024-block dispatch, prior_write folded into SV
// dispatch as HBM-bound filler blocks. Workspace ~59 MB.

typedef __attribute__((ext_vector_type(8))) short bf16x8;
typedef __attribute__((ext_vector_type(4))) float f32x4;
typedef unsigned short ushort_t;

#define DI __device__ __forceinline__

constexpr long NN = 1024L * 1024L;
constexpr long ND = 1024L * 1024L;

DI ushort_t f2bf(float f) {  // round-to-nearest-even f32 -> bf16 bits
    unsigned int u = __float_as_uint(f);
    u = u + 0x7fffu + ((u >> 16) & 1u);
    return (ushort_t)(u >> 16);
}

// ---------------------------------------------------------------------------
// m97-style GEMM body: C[128,128] tile of A[M,1024] * Bt[N,1024]^T, bf16 in,
// fp32 acc. BK=32, 4 waves (2x2), per-wave 64x64 (4x4 16x16x32 frags).
// Single-buffered 16 KB LDS, 2 barriers/K-step; relies on ~5 blocks/CU
// implicit wave overlap (m114) instead of explicit pipelining.
// OUT_F32=1: f32 out * scale; else bf16 out * scale. Epilogues LDS-staged.
// ---------------------------------------------------------------------------
template <int OUT_F32>
DI void gemm_bt_body(const ushort_t* __restrict__ A, const ushort_t* __restrict__ Bt,
                     void* __restrict__ Cout, int ldA, int ldB, int ldC,
                     float scale, int bx, int by, ushort_t* smem)
{
    ushort_t* sA = smem;          // [128][32]
    ushort_t* sB = smem + 4096;   // [128][32]

    const int tid  = threadIdx.x;
    const int wave = tid >> 6;
    const int lane = tid & 63;
    const int wm   = wave >> 1;
    const int wn   = wave & 1;
    const int bm   = bx * 128;
    const int bn   = by * 128;

    f32x4 acc[4][4];
#pragma unroll
    for (int m = 0; m < 4; ++m)
#pragma unroll
        for (int n = 0; n < 4; ++n) acc[m][n] = (f32x4){0.f, 0.f, 0.f, 0.f};

    const int  srow   = tid >> 2;
    const int  schunk = tid & 3;
    const long arow0  = (long)(bm + srow) * ldA + schunk * 8;
    const long brow0  = (long)(bn + srow) * ldB + schunk * 8;
    ushort_t* lA0 = sA + wave * 512;
    ushort_t* lA1 = sA + 2048 + wave * 512;
    ushort_t* lB0 = sB + wave * 512;
    ushort_t* lB1 = sB + 2048 + wave * 512;

    const int fra = (wm * 64 + (lane & 15)) * 32 + (lane >> 4) * 8;
    const int frb = (wn * 64 + (lane & 15)) * 32 + (lane >> 4) * 8;

    for (int k0 = 0; k0 < 1024; k0 += 32) {
        const ushort_t* ga0 = A  + arow0 + k0;
        const ushort_t* gb0 = Bt + brow0 + k0;
        __builtin_amdgcn_global_load_lds(
            (const __attribute__((address_space(1))) void*)ga0,
            (__attribute__((address_space(3))) void*)lA0, 16, 0, 0);
        __builtin_amdgcn_global_load_lds(
            (const __attribute__((address_space(1))) void*)(ga0 + (long)64 * ldA),
            (__attribute__((address_space(3))) void*)lA1, 16, 0, 0);
        __builtin_amdgcn_global_load_lds(
            (const __attribute__((address_space(1))) void*)gb0,
            (__attribute__((address_space(3))) void*)lB0, 16, 0, 0);
        __builtin_amdgcn_global_load_lds(
            (const __attribute__((address_space(1))) void*)(gb0 + (long)64 * ldB),
            (__attribute__((address_space(3))) void*)lB1, 16, 0, 0);
        __syncthreads();

        bf16x8 af[4], bfv[4];
#pragma unroll
        for (int m = 0; m < 4; ++m)
            af[m] = *(const bf16x8*)(sA + fra + m * 512);
#pragma unroll
        for (int n = 0; n < 4; ++n)
            bfv[n] = *(const bf16x8*)(sB + frb + n * 512);
#pragma unroll
        for (int m = 0; m < 4; ++m)
#pragma unroll
            for (int n = 0; n < 4; ++n)
                acc[m][n] = __builtin_amdgcn_mfma_f32_16x16x32_bf16(
                    af[m], bfv[n], acc[m][n], 0, 0, 0);
        __syncthreads();
    }

    // epilogues, LDS-staged for coalesced stores.
    // C/D frag layout (verified): col = lane&15, row = (lane>>4)*4 + r
    if (OUT_F32) {
        float* el = (float*)smem;     // [32][128] f32 = 16 KB, 4 quarters
        float* C  = (float*)Cout;
#pragma unroll
        for (int q = 0; q < 4; ++q) {
            if (wm == (q >> 1)) {
                const int mi0 = (q & 1) * 2;
#pragma unroll
                for (int mm = 0; mm < 2; ++mm)
#pragma unroll
                    for (int ni = 0; ni < 4; ++ni)
#pragma unroll
                        for (int r = 0; r < 4; ++r)
                            el[(mm * 16 + (lane >> 4) * 4 + r) * 128 +
                               wn * 64 + ni * 16 + (lane & 15)] =
                                acc[mi0 + mm][ni][r] * scale;
            }
            __syncthreads();
#pragma unroll
            for (int i = 0; i < 4; ++i) {
                const int cc  = i * 256 + tid;        // 1024 x 16B chunks
                const int row = cc >> 5;
                const int c4  = (cc & 31) * 4;
                *(float4*)&C[(long)(bm + q * 32 + row) * ldC + bn + c4] =
                    *(const float4*)&el[row * 128 + c4];
            }
            __syncthreads();
        }
    } else {
        ushort_t* el = smem;          // [64][128] ushort = 16 KB, 2 halves
        ushort_t* C  = (ushort_t*)Cout;
#pragma unroll
        for (int h = 0; h < 2; ++h) {
            if (wm == h) {
#pragma unroll
                for (int mi = 0; mi < 4; ++mi)
#pragma unroll
                    for (int ni = 0; ni < 4; ++ni)
#pragma unroll
                        for (int r = 0; r < 4; ++r)
                            el[(mi * 16 + (lane >> 4) * 4 + r) * 128 +
                               wn * 64 + ni * 16 + (lane & 15)] =
                                f2bf(acc[mi][ni][r] * scale);
            }
            __syncthreads();
#pragma unroll
            for (int i = 0; i < 4; ++i) {
                const int cc  = i * 256 + tid;        // 1024 x 16B chunks
                const int row = cc >> 4;
                const int c8  = (cc & 15) * 8;
                *(bf16x8*)&C[(long)(bm + h * 64 + row) * ldC + bn + c8] =
                    *(const bf16x8*)&el[row * 128 + c8];
            }
            __syncthreads();
        }
    }
}

template <int OUT_F32>
__global__ __launch_bounds__(256)
void gemm_bt(const ushort_t* __restrict__ A, const ushort_t* __restrict__ B,
             void* __restrict__ Cout, int ldA, int ldB, int ldC,
             long sA, long sB, long sC, float scale)
{
    __shared__ ushort_t smem[8192];
    void* C = OUT_F32 ? (void*)((float*)Cout + (long)blockIdx.z * sC)
                      : (void*)((ushort_t*)Cout + (long)blockIdx.z * sC);
    gemm_bt_body<OUT_F32>(A + (long)blockIdx.z * sA, B + (long)blockIdx.z * sB,
                          C, ldA, ldB, ldC, scale, blockIdx.x, blockIdx.y, smem);
}

// xq (M=8192,N=1024; 512 blocks) + VT (M=1024,N=8192; 512 blocks) in one
// 1024-block dispatch: 4 blocks/CU resident for better latency hiding.
__global__ __launch_bounds__(256)
void gemm_dual(const ushort_t* __restrict__ A0, const ushort_t* __restrict__ B0,
               ushort_t* __restrict__ C0,
               const ushort_t* __restrict__ A1, const ushort_t* __restrict__ B1,
               ushort_t* __restrict__ C1)
{
    __shared__ ushort_t smem[8192];
    const int id = blockIdx.x;
    if (id < 512) {   // xq: 64 x 8 tiles
        gemm_bt_body<0>(A0, B0, C0, 1024, 1024, 1024, 1.f, id >> 3, id & 7, smem);
    } else {          // VT: 8 x 64 tiles, ldC 8192
        const int j = id - 512;
        gemm_bt_body<0>(A1, B1, C1, 1024, 1024, 8192, 1.f, j & 7, j >> 3, smem);
    }
}

// SV gemm (512 blocks) + prior_write (512 HBM-bound filler blocks).
__global__ __launch_bounds__(256)
void sv_prior(const ushort_t* __restrict__ S, const ushort_t* __restrict__ VT,
              float* __restrict__ Z, const float* __restrict__ sigma,
              const float* __restrict__ batchsum, float* __restrict__ P)
{
    __shared__ ushort_t smem[8192];
    const int id = blockIdx.x;
    if (id < 512) {
        const int z = id >> 6, y = (id >> 3) & 7, x = id & 7;
        gemm_bt_body<1>(S + (long)z * ND, VT + z * 1024, Z + (long)z * ND,
                        1024, 8192, 1024, 1.f, x, y, smem);
    } else {
        const long stride = 512L * 256;
        for (long idx = (long)(id - 512) * 256 + threadIdx.x; idx < 8 * NN; idx += stride) {
            const int b   = (int)(idx >> 20);
            const int rem = (int)(idx & (NN - 1));
            const int i = rem >> 10;
            const int j = rem & 1023;
            const float sg = sigma[(b << 10) + i];
            const float d = (float)(i - j);
            P[idx] = (0.3989422804014327f / sg) *
                     __expf((-0.5f / (sg * sg)) * d * d) / batchsum[b];
        }
    }
}

// ---------------------------------------------------------------------------
// elementwise / helper kernels
// ---------------------------------------------------------------------------

// x -> bf16 AND sigma = 3^(sigmoid(5*(x.Ws))+1e-5)-1 in one pass (one wave/row)
__global__ void cvt_x_sigma(const float* __restrict__ x, const float* __restrict__ Ws,
                            ushort_t* __restrict__ xh, float* __restrict__ sigma)
{
    const int row  = blockIdx.x * 4 + (threadIdx.x >> 6);
    const int lane = threadIdx.x & 63;
    const float* xr = x + (long)row * 1024;
    float dot = 0.f;
#pragma unroll
    for (int it = 0; it < 4; ++it) {
        const int i = it * 256 + lane * 4;
        float4 v = *(const float4*)(xr + i);
        float4 w = *(const float4*)(Ws + i);
        dot += v.x * w.x + v.y * w.y + v.z * w.z + v.w * w.w;
        ushort4 o;
        o.x = f2bf(v.x); o.y = f2bf(v.y); o.z = f2bf(v.z); o.w = f2bf(v.w);
        *(ushort4*)(xh + (long)row * 1024 + i) = o;
    }
#pragma unroll
    for (int o = 32; o; o >>= 1) dot += __shfl_down(dot, o);
    if (lane == 0) {
        float s = 1.f / (1.f + __expf(-5.f * dot)) + 1e-5f;
        sigma[row] = exp2f(s * 1.5849625007211562f) - 1.f;   // 3^s - 1
    }
}

// straight f32 -> bf16 copy of Wq and Wk (no transpose needed)
__global__ void cvt_w(const float* __restrict__ Wq, const float* __restrict__ Wk,
                      ushort_t* __restrict__ Wqh, ushort_t* __restrict__ Wkh)
{
    const float* src = blockIdx.y ? Wk : Wq;
    ushort_t*    dst = blockIdx.y ? Wkh : Wqh;
    const long i = ((long)blockIdx.x * 256 + threadIdx.x) * 4;
    float4 v = *(const float4*)(src + i);
    ushort4 o;
    o.x = f2bf(v.x); o.y = f2bf(v.y); o.z = f2bf(v.z); o.w = f2bf(v.w);
    *(ushort4*)(dst + i) = o;
}

// Wv [D,D] f32 -> WvT [D,D] bf16 with WvT[n][k] = Wv[k][n]
__global__ void wt_cvt_transpose(const float* __restrict__ W, ushort_t* __restrict__ WT)
{
    __shared__ float s[64][65];
    const int tr = blockIdx.x * 64, tc = blockIdx.y * 64;
    const int t = threadIdx.x;
    const int r = t >> 4, c4 = (t & 15) * 4;
#pragma unroll
    for (int rr = r; rr < 64; rr += 16) {
        float4 v = *(const float4*)(W + (long)(tr + rr) * 1024 + tc + c4);
        s[rr][c4] = v.x; s[rr][c4 + 1] = v.y; s[rr][c4 + 2] = v.z; s[rr][c4 + 3] = v.w;
    }
    __syncthreads();
#pragma unroll
    for (int rr = r; rr < 64; rr += 16) {
        ushort4 o;
        o.x = f2bf(s[c4][rr]);     o.y = f2bf(s[c4 + 1][rr]);
        o.z = f2bf(s[c4 + 2][rr]); o.w = f2bf(s[c4 + 3][rr]);
        *(ushort4*)(WT + (long)(tc + rr) * 1024 + tr + c4) = o;
    }
}

// softmax over batch dim (8 values, stride NN)
__global__ void softmax_batch(const float* __restrict__ scores, ushort_t* __restrict__ S)
{
    const long idx = (long)blockIdx.x * 256 + threadIdx.x;
    float v[8], m = -1e30f;
#pragma unroll
    for (int b = 0; b < 8; ++b) { v[b] = scores[(long)b * NN + idx]; m = fmaxf(m, v[b]); }
    float sum = 0.f;
#pragma unroll
    for (int b = 0; b < 8; ++b) { v[b] = __expf(v[b] - m); sum += v[b]; }
    const float inv = 1.f / sum;
#pragma unroll
    for (int b = 0; b < 8; ++b) S[(long)b * NN + idx] = f2bf(v[b] * inv);
}

__global__ void prior_rowsum(const float* __restrict__ sigma, float* __restrict__ rowsum)
{
    const int row  = blockIdx.x * 4 + (threadIdx.x >> 6);
    const int lane = threadIdx.x & 63;
    const int i = row & 1023;
    const float sg = sigma[row];
    const float c = -0.5f / (sg * sg);
    float a = 0.f;
    for (int j = lane; j < 1024; j += 64) {
        float d = (float)(i - j);
        a += __expf(c * d * d);
    }
#pragma unroll
    for (int o = 32; o; o >>= 1) a += __shfl_down(a, o);
    if (lane == 0) rowsum[row] = (0.3989422804014327f / sg) * a;
}

__global__ void batch_reduce(const float* __restrict__ rowsum, float* __restrict__ batchsum)
{
    __shared__ float s[256];
    const int b = blockIdx.x, t = threadIdx.x;
    float a = 0.f;
    for (int i = t; i < 1024; i += 256) a += rowsum[b * 1024 + i];
    s[t] = a; __syncthreads();
    for (int o = 128; o; o >>= 1) { if (t < o) s[t] += s[t + o]; __syncthreads(); }
    if (t == 0) batchsum[b] = s[0];
}

// ---------------------------------------------------------------------------
extern "C" void kernel_launch(void* const* d_in, const int* in_sizes, int n_in,
                              void* d_out, int out_size, void* d_ws, size_t ws_size,
                              hipStream_t stream)
{
    const float* x  = (const float*)d_in[0];
    const float* Wq = (const float*)d_in[1];
    const float* Wk = (const float*)d_in[2];
    const float* Wv = (const float*)d_in[3];
    const float* Ws = (const float*)d_in[4];
    float* Zout = (float*)d_out;
    float* Pout = Zout + 8 * ND;

    char* base = (char*)d_ws;
    size_t off = 0;
    auto alloc = [&](size_t bytes) {
        void* p = base + off;
        off = (off + bytes + 255) & ~(size_t)255;
        return p;
    };
    ushort_t* xh    = (ushort_t*)alloc(8192L * 1024 * 2);   // 16.78 MB
    ushort_t* Wqh   = (ushort_t*)alloc(NN * 2);             //  2.10 MB
    ushort_t* Wkh   = (ushort_t*)alloc(NN * 2);             //  2.10 MB
    ushort_t* G     = (ushort_t*)alloc(NN * 2);             //  2.10 MB (Wqk^T)
    ushort_t* WvT   = (ushort_t*)alloc(NN * 2);             //  2.10 MB
    ushort_t* xqh   = (ushort_t*)alloc(8192L * 1024 * 2);   // 16.78 MB
    ushort_t* VTall = (ushort_t*)alloc(1024L * 8192 * 2);   // 16.78 MB
    float* sigma    = (float*)alloc(8192 * 4);
    float* rowsum   = (float*)alloc(8192 * 4);
    float* batchsum = (float*)alloc(64);
    // overlays: scores (f32) -> Pout (dead until sv_prior's filler blocks,
    //           which run after softmax consumed scores);
    //           S (bf16) -> xh (dead after scores gemm)
    float*    scores = Pout;
    ushort_t* Sh     = xh;

    // 1. x -> bf16 + sigma (fused)
    cvt_x_sigma<<<2048, 256, 0, stream>>>(x, Ws, xh, sigma);
    // 2. weights: Wq,Wk straight bf16 copies; WvT transpose
    cvt_w<<<dim3(1024, 2), 256, 0, stream>>>(Wq, Wk, Wqh, Wkh);
    wt_cvt_transpose<<<dim3(16, 16), 256, 0, stream>>>(Wv, WvT);
    // 3. prior partial sums (needs only sigma)
    prior_rowsum<<<2048, 256, 0, stream>>>(sigma, rowsum);
    batch_reduce<<<8, 256, 0, stream>>>(rowsum, batchsum);
    // 4. G[j,k] = sum_i Wk[j,i]*Wq[k,i] = (Wq Wk^T)^T  -> Bt operand for xq
    gemm_bt<0><<<dim3(8, 8, 1), 256, 0, stream>>>(
        Wkh, Wqh, G, 1024, 1024, 1024, 0, 0, 0, 1.f);
    // 5. xq = x*(Wq Wk^T)  AND  VT = Wv^T x^T, one 1024-block dispatch
    gemm_dual<<<1024, 256, 0, stream>>>(xh, G, xqh, WvT, xh, VTall);
    // 6. scores = xq x^T / 32  (per batch, f32 -> Pout scratch), 512 blocks
    gemm_bt<1><<<dim3(8, 8, 8), 256, 0, stream>>>(
        xqh, xh, scores, 1024, 1024, 1024, ND, ND, NN, 0.03125f);
    // 7. softmax over batch -> S (bf16, overlays xh)
    softmax_batch<<<4096, 256, 0, stream>>>(scores, Sh);
    // 8. Z = S V (512 gemm blocks) + prior P write (512 filler blocks)
    sv_prior<<<1024, 256, 0, stream>>>(Sh, VTall, Zout, sigma, batchsum, Pout);
}

// Round 6
// 161.963 us; speedup vs baseline: 1.4536x; 1.4536x over previous
//
#include <hip/hip_runtime.h>

// AnomalyAttention forward, MI355X gfx950.
// B=8, N=1024, D=1024. Out = [Z (8*1024*1024 f32), P (8*1024*1024 f32)].
// Round 6: round-3 gemm3b (verified) + bijective XCD-chunk swizzle with
// per-GEMM decode order (each XCD chunk's working set <= 4MB L2), G-trick
// (scores = (x*G)*x^T), prior_rowsum fused into cvt_x_sigma.
// Workspace ~59 MB; scores scratch overlays Pout.

typedef __attribute__((ext_vector_type(8))) short bf16x8;
typedef __attribute__((ext_vector_type(4))) float f32x4;
typedef unsigned short ushort_t;

#define DI __device__ __forceinline__

constexpr long NN = 1024L * 1024L;
constexpr long ND = 1024L * 1024L;

DI ushort_t f2bf(float f) {  // round-to-nearest-even f32 -> bf16 bits
    unsigned int u = __float_as_uint(f);
    u = u + 0x7fffu + ((u >> 16) & 1u);
    return (ushort_t)(u >> 16);
}

// ---------------------------------------------------------------------------
// Pipelined GEMM: C[M,N] = A[M,K=1024] * Bt[N,K=1024]^T, bf16 in, fp32 acc.
// Tile 128x256, BK=64, 8 waves (2M x 4N), per-wave 64x64 (4x4 16x16x32 frags).
// LDS: 3 buffers, XOR-swizzled (byte ^= (row&7)<<4); linear gload_lds dest +
// inverse-swizzled global source. Schedule: 2 phases/K-tile, prefetch
// distance 2, vmcnt(6). (Sync structure identical to verified round-3 kernel.)
//
// Block decode: 1D grid, bijective XCD-chunk swizzle (total%8==0):
//   swz = (lin&7)*(total/8) + (lin>>3)   -> XCD k owns swz in [k*q, (k+1)*q)
// then swz -> (c0, c1, bz) with c0 fastest; xfirst picks bx=c0 or by=c0.
// Chosen per GEMM so each XCD chunk's operand working set fits 4MB L2.
// ---------------------------------------------------------------------------
template <int OUT_BF16>
__global__ __launch_bounds__(512, 2)
void gemm3b(const ushort_t* __restrict__ A, const ushort_t* __restrict__ B,
            void* __restrict__ Cout, int ldA, int ldB, int ldC,
            long sA, long sB, long sC, float scale,
            int n0, int n1, int xfirst)
{
    __shared__ ushort_t lds[3][24576];   // per buf: A 8192 + B 16384 ushorts
    constexpr int B_OFF = 8192;

    // ---- block decode with XCD-chunk swizzle ----
    const int total = gridDim.x;
    const int lin   = blockIdx.x;
    const int swz   = (lin & 7) * (total >> 3) + (lin >> 3);
    const int c0    = swz % n0;
    const int rem   = swz / n0;
    const int c1    = rem % n1;
    const int bz    = rem / n1;
    const int bx    = xfirst ? c0 : c1;
    const int by    = xfirst ? c1 : c0;

    const int tid  = threadIdx.x;
    const int wave = tid >> 6;
    const int lane = tid & 63;
    const int wm   = wave >> 2;   // 0..1
    const int wn   = wave & 3;    // 0..3
    const int gm   = bx * 128;
    const int gn   = by * 256;
    const ushort_t* Ab = A + (long)bz * sA;
    const ushort_t* Bb = B + (long)bz * sB;

    // staging: thread t loads 16B; row in 64-row half = tid>>3,
    // swizzled source col chunk = (tid&7) ^ (row&7)
    const int srow = tid >> 3;
    const int scol = 8 * ((tid & 7) ^ (srow & 7));
    const int sdst = wave * 512;   // wave-uniform LDS dest offset (ushorts)

    auto stageA = [&](int t, int d, int h) {
        const ushort_t* src = Ab + (long)(gm + h * 64 + srow) * ldA + t * 64 + scol;
        __builtin_amdgcn_global_load_lds(
            (const __attribute__((address_space(1))) void*)src,
            (__attribute__((address_space(3))) void*)(&lds[d][h * 4096 + sdst]),
            16, 0, 0);
    };
    auto stageB = [&](int t, int d, int h, int j) {
        const ushort_t* src = Bb + (long)(gn + h * 128 + j * 64 + srow) * ldB + t * 64 + scol;
        __builtin_amdgcn_global_load_lds(
            (const __attribute__((address_space(1))) void*)src,
            (__attribute__((address_space(3))) void*)(&lds[d][B_OFF + h * 8192 + j * 4096 + sdst]),
            16, 0, 0);
    };

    // fragment reads: row = base + (lane&15); swizzle uses row&7 == lane&7
    const int arow = wm * 64 + (lane & 15);
    const int brow = wn * 64 + (lane & 15);
    const int cs0 = (((lane >> 4) * 16) ^ ((lane & 7) << 4)) >> 1;        // ushorts
    const int cs1 = ((64 + (lane >> 4) * 16) ^ ((lane & 7) << 4)) >> 1;

    f32x4 acc[4][4];
#pragma unroll
    for (int m = 0; m < 4; ++m)
#pragma unroll
        for (int n = 0; n < 4; ++n) acc[m][n] = (f32x4){0.f, 0.f, 0.f, 0.f};

    // prologue: tile0 -> buf0, tile1 -> buf1 (6 loads each)
    stageA(0, 0, 0); stageA(0, 0, 1);
    stageB(0, 0, 0, 0); stageB(0, 0, 0, 1); stageB(0, 0, 1, 0); stageB(0, 0, 1, 1);
    stageA(1, 1, 0); stageA(1, 1, 1);
    stageB(1, 1, 0, 0); stageB(1, 1, 0, 1); stageB(1, 1, 1, 0); stageB(1, 1, 1, 1);
    asm volatile("s_waitcnt vmcnt(6)" ::: "memory");   // tile0 resident
    __builtin_amdgcn_s_barrier();
    __builtin_amdgcn_sched_barrier(0);

    int cur = 0;
    for (int t = 0; t < 16; ++t) {
        const int nxt = (cur == 0) ? 2 : cur - 1;      // (t+2)%3
        const ushort_t* la = &lds[cur][0];
        const ushort_t* lb = &lds[cur][B_OFF];

        bf16x8 a[2][4], b[2][4];
        // ---- phase 1 ----
#pragma unroll
        for (int mi = 0; mi < 4; ++mi) {
            a[0][mi] = *(const bf16x8*)&la[(arow + mi * 16) * 64 + cs0];
            a[1][mi] = *(const bf16x8*)&la[(arow + mi * 16) * 64 + cs1];
        }
#pragma unroll
        for (int ni = 0; ni < 2; ++ni) {
            b[0][ni] = *(const bf16x8*)&lb[(brow + ni * 16) * 64 + cs0];
            b[1][ni] = *(const bf16x8*)&lb[(brow + ni * 16) * 64 + cs1];
        }
        if (t < 14) {
            stageB(t + 2, nxt, 0, 0); stageB(t + 2, nxt, 0, 1);
            stageB(t + 2, nxt, 1, 0); stageB(t + 2, nxt, 1, 1);
        }
        __builtin_amdgcn_s_barrier();
        asm volatile("s_waitcnt lgkmcnt(0)" ::: "memory");
        __builtin_amdgcn_sched_barrier(0);
        __builtin_amdgcn_s_setprio(1);
#pragma unroll
        for (int mi = 0; mi < 4; ++mi)
#pragma unroll
            for (int ni = 0; ni < 2; ++ni) {
                acc[mi][ni] = __builtin_amdgcn_mfma_f32_16x16x32_bf16(a[0][mi], b[0][ni], acc[mi][ni], 0, 0, 0);
                acc[mi][ni] = __builtin_amdgcn_mfma_f32_16x16x32_bf16(a[1][mi], b[1][ni], acc[mi][ni], 0, 0, 0);
            }
        __builtin_amdgcn_s_setprio(0);
        __builtin_amdgcn_s_barrier();
        __builtin_amdgcn_sched_barrier(0);

        // ---- phase 2 ----
#pragma unroll
        for (int ni = 2; ni < 4; ++ni) {
            b[0][ni] = *(const bf16x8*)&lb[(brow + ni * 16) * 64 + cs0];
            b[1][ni] = *(const bf16x8*)&lb[(brow + ni * 16) * 64 + cs1];
        }
        if (t < 14) { stageA(t + 2, nxt, 0); stageA(t + 2, nxt, 1); }
        __builtin_amdgcn_s_barrier();
        asm volatile("s_waitcnt lgkmcnt(0)" ::: "memory");
        if (t < 14) asm volatile("s_waitcnt vmcnt(6)" ::: "memory");  // tile t+1 landed
        else        asm volatile("s_waitcnt vmcnt(0)" ::: "memory");
        __builtin_amdgcn_sched_barrier(0);
        __builtin_amdgcn_s_setprio(1);
#pragma unroll
        for (int mi = 0; mi < 4; ++mi)
#pragma unroll
            for (int ni = 2; ni < 4; ++ni) {
                acc[mi][ni] = __builtin_amdgcn_mfma_f32_16x16x32_bf16(a[0][mi], b[0][ni], acc[mi][ni], 0, 0, 0);
                acc[mi][ni] = __builtin_amdgcn_mfma_f32_16x16x32_bf16(a[1][mi], b[1][ni], acc[mi][ni], 0, 0, 0);
            }
        __builtin_amdgcn_s_setprio(0);
        __builtin_amdgcn_s_barrier();
        __builtin_amdgcn_sched_barrier(0);

        cur = (cur == 2) ? 0 : cur + 1;
    }

    // epilogue. C/D layout (verified): col = lane&15, row = (lane>>4)*4 + r
    if (OUT_BF16) {
        ushort_t* el = &lds[0][0];   // [128][256] ushort = 64 KB
#pragma unroll
        for (int mi = 0; mi < 4; ++mi)
#pragma unroll
            for (int ni = 0; ni < 4; ++ni)
#pragma unroll
                for (int r = 0; r < 4; ++r)
                    el[(wm * 64 + mi * 16 + (lane >> 4) * 4 + r) * 256 +
                       wn * 64 + ni * 16 + (lane & 15)] = f2bf(acc[mi][ni][r] * scale);
        __builtin_amdgcn_s_barrier();
        ushort_t* C = (ushort_t*)Cout + (long)bz * sC;
#pragma unroll
        for (int rr = 0; rr < 8; ++rr) {
            const int row = rr * 16 + (tid >> 5);
            const int col = (tid & 31) * 8;
            *(bf16x8*)&C[(long)(gm + row) * ldC + gn + col] =
                *(const bf16x8*)&el[row * 256 + col];
        }
    } else {
        // two 64-row halves staged through LDS for coalesced float4 stores
        float* el = (float*)&lds[0][0];   // [64][256] f32 = 64 KB
        float* C  = (float*)Cout + (long)bz * sC;
#pragma unroll
        for (int h = 0; h < 2; ++h) {
            if (wm == h) {
#pragma unroll
                for (int mi = 0; mi < 4; ++mi)
#pragma unroll
                    for (int ni = 0; ni < 4; ++ni)
#pragma unroll
                        for (int r = 0; r < 4; ++r)
                            el[(mi * 16 + (lane >> 4) * 4 + r) * 256 +
                               wn * 64 + ni * 16 + (lane & 15)] = acc[mi][ni][r] * scale;
            }
            __builtin_amdgcn_s_barrier();
#pragma unroll
            for (int i = 0; i < 8; ++i) {
                const int cc  = i * 512 + tid;      // 16B chunk id, 0..4095
                const int row = cc >> 6;
                const int c4  = (cc & 63) * 4;
                *(float4*)&C[(long)(gm + h * 64 + row) * ldC + gn + c4] =
                    *(const float4*)&el[row * 256 + c4];
            }
            __builtin_amdgcn_s_barrier();
        }
    }
}

// ---------------------------------------------------------------------------
// elementwise / helper kernels
// ---------------------------------------------------------------------------

// one wave per row: x -> bf16, sigma = 3^(sigmoid(5*(x.Ws))+1e-5)-1, and
// prior rowsum = inv_norm * sum_j exp(-0.5((i-j)/sg)^2), all fused.
__global__ void cvt_x_sigma_rowsum(const float* __restrict__ x, const float* __restrict__ Ws,
                                   ushort_t* __restrict__ xh, float* __restrict__ sigma,
                                   float* __restrict__ rowsum)
{
    const int row  = blockIdx.x * 4 + (threadIdx.x >> 6);
    const int lane = threadIdx.x & 63;
    const float* xr = x + (long)row * 1024;
    float dot = 0.f;
#pragma unroll
    for (int it = 0; it < 4; ++it) {
        const int i = it * 256 + lane * 4;
        float4 v = *(const float4*)(xr + i);
        float4 w = *(const float4*)(Ws + i);
        dot += v.x * w.x + v.y * w.y + v.z * w.z + v.w * w.w;
        ushort4 o;
        o.x = f2bf(v.x); o.y = f2bf(v.y); o.z = f2bf(v.z); o.w = f2bf(v.w);
        *(ushort4*)(xh + (long)row * 1024 + i) = o;
    }
#pragma unroll
    for (int o = 32; o; o >>= 1) dot += __shfl_down(dot, o);
    float sg;
    if (lane == 0) {
        float s = 1.f / (1.f + __expf(-5.f * dot)) + 1e-5f;
        sg = exp2f(s * 1.5849625007211562f) - 1.f;   // 3^s - 1
    }
    sg = __shfl(sg, 0);
    // prior row-sum for this row (i = row mod 1024)
    const int i = row & 1023;
    const float c = -0.5f / (sg * sg);
    float a = 0.f;
    for (int j = lane; j < 1024; j += 64) {
        float d = (float)(i - j);
        a += __expf(c * d * d);
    }
#pragma unroll
    for (int o = 32; o; o >>= 1) a += __shfl_down(a, o);
    if (lane == 0) {
        sigma[row]  = sg;
        rowsum[row] = (0.3989422804014327f / sg) * a;
    }
}

// straight f32 -> bf16 copy of Wq and Wk (no transpose needed for G)
__global__ void cvt_w(const float* __restrict__ Wq, const float* __restrict__ Wk,
                      ushort_t* __restrict__ Wqh, ushort_t* __restrict__ Wkh)
{
    const float* src = blockIdx.y ? Wk : Wq;
    ushort_t*    dst = blockIdx.y ? Wkh : Wqh;
    const long i = ((long)blockIdx.x * 256 + threadIdx.x) * 4;
    float4 v = *(const float4*)(src + i);
    ushort4 o;
    o.x = f2bf(v.x); o.y = f2bf(v.y); o.z = f2bf(v.z); o.w = f2bf(v.w);
    *(ushort4*)(dst + i) = o;
}

// Wv [D,D] f32 -> WvT [D,D] bf16 with WvT[n][k] = Wv[k][n]
__global__ void wt_cvt_transpose(const float* __restrict__ W, ushort_t* __restrict__ WT)
{
    __shared__ float s[64][65];
    const int tr = blockIdx.x * 64, tc = blockIdx.y * 64;
    const int t = threadIdx.x;
    const int r = t >> 4, c4 = (t & 15) * 4;
#pragma unroll
    for (int rr = r; rr < 64; rr += 16) {
        float4 v = *(const float4*)(W + (long)(tr + rr) * 1024 + tc + c4);
        s[rr][c4] = v.x; s[rr][c4 + 1] = v.y; s[rr][c4 + 2] = v.z; s[rr][c4 + 3] = v.w;
    }
    __syncthreads();
#pragma unroll
    for (int rr = r; rr < 64; rr += 16) {
        ushort4 o;
        o.x = f2bf(s[c4][rr]);     o.y = f2bf(s[c4 + 1][rr]);
        o.z = f2bf(s[c4 + 2][rr]); o.w = f2bf(s[c4 + 3][rr]);
        *(ushort4*)(WT + (long)(tc + rr) * 1024 + tr + c4) = o;
    }
}

// softmax over batch dim (8 values, stride NN)
__global__ void softmax_batch(const float* __restrict__ scores, ushort_t* __restrict__ S)
{
    const long idx = (long)blockIdx.x * 256 + threadIdx.x;
    float v[8], m = -1e30f;
#pragma unroll
    for (int b = 0; b < 8; ++b) { v[b] = scores[(long)b * NN + idx]; m = fmaxf(m, v[b]); }
    float sum = 0.f;
#pragma unroll
    for (int b = 0; b < 8; ++b) { v[b] = __expf(v[b] - m); sum += v[b]; }
    const float inv = 1.f / sum;
#pragma unroll
    for (int b = 0; b < 8; ++b) S[(long)b * NN + idx] = f2bf(v[b] * inv);
}

__global__ void batch_reduce(const float* __restrict__ rowsum, float* __restrict__ batchsum)
{
    __shared__ float s[256];
    const int b = blockIdx.x, t = threadIdx.x;
    float a = 0.f;
    for (int i = t; i < 1024; i += 256) a += rowsum[b * 1024 + i];
    s[t] = a; __syncthreads();
    for (int o = 128; o; o >>= 1) { if (t < o) s[t] += s[t + o]; __syncthreads(); }
    if (t == 0) batchsum[b] = s[0];
}

__global__ void prior_write(const float* __restrict__ sigma, const float* __restrict__ batchsum,
                            float* __restrict__ P)
{
    const long stride = (long)gridDim.x * 256;
    for (long idx = (long)blockIdx.x * 256 + threadIdx.x; idx < 8 * NN; idx += stride) {
        const int b   = (int)(idx >> 20);
        const int rem = (int)(idx & (NN - 1));
        const int i = rem >> 10;
        const int j = rem & 1023;
        const float sg = sigma[(b << 10) + i];
        const float d = (float)(i - j);
        P[idx] = (0.3989422804014327f / sg) *
                 __expf((-0.5f / (sg * sg)) * d * d) / batchsum[b];
    }
}

// ---------------------------------------------------------------------------
extern "C" void kernel_launch(void* const* d_in, const int* in_sizes, int n_in,
                              void* d_out, int out_size, void* d_ws, size_t ws_size,
                              hipStream_t stream)
{
    const float* x  = (const float*)d_in[0];
    const float* Wq = (const float*)d_in[1];
    const float* Wk = (const float*)d_in[2];
    const float* Wv = (const float*)d_in[3];
    const float* Ws = (const float*)d_in[4];
    float* Zout = (float*)d_out;
    float* Pout = Zout + 8 * ND;

    char* base = (char*)d_ws;
    size_t off = 0;
    auto alloc = [&](size_t bytes) {
        void* p = base + off;
        off = (off + bytes + 255) & ~(size_t)255;
        return p;
    };
    ushort_t* xh    = (ushort_t*)alloc(8192L * 1024 * 2);   // 16.78 MB
    ushort_t* Wqh   = (ushort_t*)alloc(NN * 2);             //  2.10 MB
    ushort_t* Wkh   = (ushort_t*)alloc(NN * 2);             //  2.10 MB
    ushort_t* G     = (ushort_t*)alloc(NN * 2);             //  2.10 MB
    ushort_t* WvT   = (ushort_t*)alloc(NN * 2);             //  2.10 MB
    ushort_t* xqh   = (ushort_t*)alloc(8192L * 1024 * 2);   // 16.78 MB
    ushort_t* VTall = (ushort_t*)alloc(1024L * 8192 * 2);   // 16.78 MB
    float* sigma    = (float*)alloc(8192 * 4);
    float* rowsum   = (float*)alloc(8192 * 4);
    float* batchsum = (float*)alloc(64);
    // overlays: scores (f32) -> Pout (dead until prior_write, which runs
    //           after softmax consumed scores); S (bf16) -> xh (x-input dead
    //           after scores gemm)
    float*    scores = Pout;
    ushort_t* Sh     = xh;

    // 1. x -> bf16 + sigma + prior rowsum (fused, one wave per row)
    cvt_x_sigma_rowsum<<<2048, 256, 0, stream>>>(x, Ws, xh, sigma, rowsum);
    // 2. weights: Wq,Wk straight bf16 copies; WvT transpose
    cvt_w<<<dim3(1024, 2), 256, 0, stream>>>(Wq, Wk, Wqh, Wkh);
    wt_cvt_transpose<<<dim3(16, 16), 256, 0, stream>>>(Wv, WvT);
    batch_reduce<<<8, 256, 0, stream>>>(rowsum, batchsum);
    // 3. G[j,k] = sum_i Wk[j,i]*Wq[k,i]  (M=1024,N=1024; 32 blocks)
    gemm3b<1><<<32, 512, 0, stream>>>(
        Wkh, Wqh, G, 1024, 1024, 1024, 0, 0, 0, 1.f, 8, 4, 1);
    // 4. xq = x*(Wq Wk^T)  (M=8192,N=1024; 256 blocks, by-fastest:
    //    XCD chunk = 8 A-tiles (2MB) + G (2MB))
    gemm3b<1><<<256, 512, 0, stream>>>(
        xh, G, xqh, 1024, 1024, 1024, 0, 0, 0, 1.f, 4, 64, 0);
    // 5. VT = Wv^T x^T  (M=1024,N=8192; 256 blocks, bx-fastest:
    //    XCD chunk = 4 B-panels (2MB) + WvT (2MB))
    gemm3b<1><<<256, 512, 0, stream>>>(
        WvT, xh, VTall, 1024, 1024, 8192, 0, 0, 0, 1.f, 8, 32, 1);
    // 6. scores = xq x^T / 32  (per batch; 256 blocks, one batch per XCD:
    //    chunk = xq_b (2MB) + x_b (2MB))
    gemm3b<0><<<256, 512, 0, stream>>>(
        xqh, xh, scores, 1024, 1024, 1024, ND, ND, NN, 0.03125f, 8, 4, 1);
    // 7. softmax over batch -> S (bf16, overlays xh)
    softmax_batch<<<4096, 256, 0, stream>>>(scores, Sh);
    // 8. Z = S V  (per batch; 256 blocks, one batch per XCD:
    //    chunk = S_b (2MB) + VT_b (2MB))
    gemm3b<0><<<256, 512, 0, stream>>>(
        Sh, VTall, Zout, 1024, 8192, 1024, NN, 1024, ND, 1.f, 8, 4, 1);
    // 9. prior P (fp32 exact, deterministic; overwrites scores scratch)
    prior_write<<<2048, 256, 0, stream>>>(sigma, batchsum, Pout);
}